// Round 20
// baseline (147.674 us; speedup 1.0000x reference)
//
#include <hip/hip_runtime.h>
#include <hip/hip_bf16.h>

// MultiDiffHeadAttention. B=2, T=2048, E=1024, H=8, HS=64, DO=128.
// mask = tril(ones, diagonal=1): (t,s) allowed iff s <= t+1.
// R20 = R19 with attention software-pipelined across tiles (T15 att[2]):
// carry QK scores s4 in regs across the barrier; each iter issues QK[t+1]
// (K 3-deep rotation) before softmax[t]+PV[t], so independent MFMAs cover
// the softmax VALU + P LDS round-trip. Single barrier/tile kept.
// prep / qkv_mfma2 / proj_mfma2 verbatim from R19.

constexpr int Tn = 2048;
constexpr int En = 1024;
constexpr int Hn = 8;
constexpr float LAMBDA_INIT = 0.8f;
// 0.125 (HS^-0.5) * log2(e), folded into Q at projection time.
constexpr float QSCALE = 0.18033688011112042f;
constexpr size_t SZb = (size_t)2 * Tn * En;      // 4,194,304 elems
constexpr size_t WSZ = (size_t)En * En;          // 1,048,576 elems

typedef __attribute__((ext_vector_type(8))) short short8;
typedef __attribute__((ext_vector_type(4))) short s16x4;
typedef __attribute__((ext_vector_type(4))) float f32x4;

__device__ __forceinline__ short f2bf(float x) {
  union { __hip_bfloat16 h; short s; } u;
  u.h = __float2bfloat16(x);
  return u.s;
}
__device__ __forceinline__ void gload16(const short* g, short* l) {
  __builtin_amdgcn_global_load_lds(
      (const __attribute__((address_space(1))) void*)g,
      (__attribute__((address_space(3))) void*)l, 16, 0, 0);
}

// ---------------- prepass (merged): cvt q/k/v + transpose weights -------
// grid 7168: ids [0,6144) = cvt (by=id/2048, bx=id%2048); [6144,7168) = twt.
__global__ __launch_bounds__(256)
void prep(const float* __restrict__ q, const float* __restrict__ k,
          const float* __restrict__ v,
          const float* __restrict__ Wq, const float* __restrict__ Wk,
          const float* __restrict__ Wv, const float* __restrict__ Wp,
          short* __restrict__ ws, short* __restrict__ WT) {
  __shared__ float tl[64][65];
  const int id = blockIdx.x;
  const int tid = threadIdx.x;
  if (id < 6144) {
    const int by = id >> 11;          // 0..2 (q/k/v)
    const int bx = id & 2047;
    const float* src = (by == 0) ? q : (by == 1) ? k : v;
    short* dst = ws + (size_t)by * SZb;
    const size_t i = ((size_t)bx * 256 + tid) * 8;
    float4 a = *(const float4*)&src[i];
    float4 b = *(const float4*)&src[i + 4];
    short8 o;
    o[0] = f2bf(a.x); o[1] = f2bf(a.y); o[2] = f2bf(a.z); o[3] = f2bf(a.w);
    o[4] = f2bf(b.x); o[5] = f2bf(b.y); o[6] = f2bf(b.z); o[7] = f2bf(b.w);
    *(short8*)&dst[i] = o;
    return;
  }
  const int wid = id - 6144;          // 0..1023
  const float* src;
  short* dst;
  int r0, c0, C;
  if (wid < 768) {
    const int wi = wid >> 8;
    const float* W = (wi == 0) ? Wq : (wi == 1) ? Wk : Wv;
    const int rem = wid & 255;
    const int h = rem >> 5;
    const int tile = rem & 31;        // 16 k-tiles x 2 n-tiles
    r0 = (tile >> 1) * 64;
    c0 = (tile & 1) * 64;
    C = 128;
    src = W + (size_t)h * En * 128;
    dst = WT + (size_t)wi * WSZ + (size_t)h * 128 * En;
  } else {
    const int idx = wid - 768;        // 16x16 tiles
    r0 = (idx >> 4) * 64;
    c0 = (idx & 15) * 64;
    C = En;
    src = Wp;
    dst = WT + 3 * WSZ;
  }
  const int r = tid >> 2, cc = (tid & 3) * 16;
#pragma unroll
  for (int j = 0; j < 4; ++j) {
    const float4 x = *(const float4*)&src[(size_t)(r0 + r) * C + c0 + cc + j * 4];
    tl[r][cc + j * 4 + 0] = x.x;
    tl[r][cc + j * 4 + 1] = x.y;
    tl[r][cc + j * 4 + 2] = x.z;
    tl[r][cc + j * 4 + 3] = x.w;
  }
  __syncthreads();
  const int c = tid >> 2, rc = (tid & 3) * 16;
  short8 o0, o1;
#pragma unroll
  for (int e = 0; e < 8; ++e) {
    o0[e] = f2bf(tl[rc + e][c]);
    o1[e] = f2bf(tl[rc + 8 + e][c]);
  }
  *(short8*)&dst[(size_t)(c0 + c) * En + r0 + rc] = o0;
  *(short8*)&dst[(size_t)(c0 + c) * En + r0 + rc + 8] = o1;
}

// ---------------- QKV projection: pure-bf16 gload_lds MFMA (R13) --------
__global__ __launch_bounds__(256)
void qkv_mfma2(const short* __restrict__ Xq, const short* __restrict__ Xk,
               const short* __restrict__ Xv, const short* __restrict__ WT,
               short* __restrict__ Qo, short* __restrict__ Ko,
               short* __restrict__ Vto) {
  __shared__ __align__(16) short As[2][4096];   // [row][32]
  __shared__ __align__(16) short Bs2[2][4096];  // [n][32]
  const int which = blockIdx.z;
  const short* X = (which == 0) ? Xq : (which == 1) ? Xk : Xv;
  const int head = blockIdx.y;
  const int m0 = blockIdx.x * 128;
  const short* Bt = WT + (size_t)which * WSZ + (size_t)head * 128 * En;
  const float oscale = (which == 0) ? QSCALE : 1.0f;

  const int tid = threadIdx.x;
  const int lane = tid & 63;
  const int w = tid >> 6, wr = w >> 1, wc = w & 1;
  const int fr = lane & 15, fk = (lane >> 4) * 8;
  const int srow = tid >> 2, sch = (tid & 3) * 8;  // staging row/chunk
  const int wdst = w * 512;                        // wave-uniform LDS base

#define QSTAGE(BUF, K0)                                                  \
  {                                                                      \
    _Pragma("unroll") for (int j = 0; j < 2; ++j) {                      \
      gload16(&X[(size_t)(m0 + j * 64 + srow) * En + (K0) + sch],        \
              &As[BUF][j * 2048 + wdst]);                                \
      gload16(&Bt[(size_t)(j * 64 + srow) * En + (K0) + sch],            \
              &Bs2[BUF][j * 2048 + wdst]);                               \
    }                                                                    \
  }

  f32x4 acc[4][4] = {};
  QSTAGE(0, 0);
  for (int k0 = 0; k0 < En; k0 += 32) {
    const int cur = (k0 >> 5) & 1;
    if (k0 + 32 < En) {
      QSTAGE(cur ^ 1, k0 + 32);
      __builtin_amdgcn_sched_barrier(0);
      asm volatile("s_waitcnt vmcnt(4)" ::: "memory");
      __builtin_amdgcn_sched_barrier(0);
    } else {
      __builtin_amdgcn_sched_barrier(0);
      asm volatile("s_waitcnt vmcnt(0)" ::: "memory");
      __builtin_amdgcn_sched_barrier(0);
    }
    __builtin_amdgcn_s_barrier();  // tile cur in LDS for all waves

    short8 a[4], b[4];
#pragma unroll
    for (int i = 0; i < 4; ++i)
      a[i] = *(const short8*)&As[cur][(wr * 64 + i * 16 + fr) * 32 + fk];
#pragma unroll
    for (int j = 0; j < 4; ++j)
      b[j] = *(const short8*)&Bs2[cur][(wc * 64 + j * 16 + fr) * 32 + fk];
#pragma unroll
    for (int i = 0; i < 4; ++i)
#pragma unroll
      for (int j = 0; j < 4; ++j)
        acc[i][j] = __builtin_amdgcn_mfma_f32_16x16x32_bf16(a[i], b[j],
                                                            acc[i][j], 0, 0, 0);
    __builtin_amdgcn_s_barrier();  // reads of cur retired before restage
  }
#undef QSTAGE

  const int crow = (lane >> 4) * 4, ccol = lane & 15;
  if (which == 2) {
#pragma unroll
    for (int i = 0; i < 4; ++i) {
      const int m = m0 + wr * 64 + i * 16 + crow;
      const int bb = m >> 11, t = m & (Tn - 1);
#pragma unroll
      for (int j = 0; j < 4; ++j) {
        const int d = wc * 64 + j * 16 + ccol;
        s16x4 pk;
#pragma unroll
        for (int p = 0; p < 4; ++p) pk[p] = f2bf(acc[i][j][p]);
        *(s16x4*)&Vto[((size_t)(bb * Hn + head) * 128 + d) * Tn + t] = pk;
      }
    }
  } else {
    short* Out = (which == 0) ? Qo : Ko;
#pragma unroll
    for (int i = 0; i < 4; ++i) {
      const int m = m0 + wr * 64 + i * 16 + crow;
      const int bb = m >> 11, t = m & (Tn - 1);
      short* dst = Out + ((size_t)(bb * Hn + head) * Tn + t) * 128;
#pragma unroll
      for (int j = 0; j < 4; ++j) {
        const int d = wc * 64 + j * 16 + ccol;
#pragma unroll
        for (int p = 0; p < 4; ++p)
          dst[(size_t)p * 128 + d] = f2bf(acc[i][j][p] * oscale);
      }
    }
  }
}

// ---------------- Output projection: pure-bf16 gload_lds MFMA (R13) -----
__global__ __launch_bounds__(256)
void proj_mfma2(const short* __restrict__ Xb, const short* __restrict__ WpT,
                const float* __restrict__ bias, float* __restrict__ Out) {
  __shared__ __align__(16) short As[2][2048];   // [64][32]
  __shared__ __align__(16) short Bs2[2][4096];  // [128][32]
  const int m0 = blockIdx.x * 64;
  const int n0 = blockIdx.y * 128;

  const int tid = threadIdx.x;
  const int lane = tid & 63;
  const int w = tid >> 6, wr = w >> 1, wc = w & 1;
  const int fr = lane & 15, fk = (lane >> 4) * 8;
  const int srow = tid >> 2, sch = (tid & 3) * 8;
  const int wdst = w * 512;

#define PSTAGE(BUF, K0)                                                  \
  {                                                                      \
    gload16(&Xb[(size_t)(m0 + srow) * En + (K0) + sch],                  \
            &As[BUF][wdst]);                                             \
    _Pragma("unroll") for (int j = 0; j < 2; ++j)                        \
      gload16(&WpT[(size_t)(n0 + j * 64 + srow) * En + (K0) + sch],      \
              &Bs2[BUF][j * 2048 + wdst]);                               \
  }

  f32x4 acc[2][4] = {};
  PSTAGE(0, 0);
  for (int k0 = 0; k0 < En; k0 += 32) {
    const int cur = (k0 >> 5) & 1;
    if (k0 + 32 < En) {
      PSTAGE(cur ^ 1, k0 + 32);
      __builtin_amdgcn_sched_barrier(0);
      asm volatile("s_waitcnt vmcnt(3)" ::: "memory");
      __builtin_amdgcn_sched_barrier(0);
    } else {
      __builtin_amdgcn_sched_barrier(0);
      asm volatile("s_waitcnt vmcnt(0)" ::: "memory");
      __builtin_amdgcn_sched_barrier(0);
    }
    __builtin_amdgcn_s_barrier();

    short8 a[2], b[4];
#pragma unroll
    for (int i = 0; i < 2; ++i)
      a[i] = *(const short8*)&As[cur][(wr * 32 + i * 16 + fr) * 32 + fk];
#pragma unroll
    for (int j = 0; j < 4; ++j)
      b[j] = *(const short8*)&Bs2[cur][(wc * 64 + j * 16 + fr) * 32 + fk];
#pragma unroll
    for (int i = 0; i < 2; ++i)
#pragma unroll
      for (int j = 0; j < 4; ++j)
        acc[i][j] = __builtin_amdgcn_mfma_f32_16x16x32_bf16(a[i], b[j],
                                                            acc[i][j], 0, 0, 0);
    __builtin_amdgcn_s_barrier();
  }
#undef PSTAGE

  const int crow = (lane >> 4) * 4, ccol = lane & 15;
#pragma unroll
  for (int i = 0; i < 2; ++i) {
    const int m = m0 + wr * 32 + i * 16 + crow;
#pragma unroll
    for (int j = 0; j < 4; ++j) {
      const int n = n0 + wc * 64 + j * 16 + ccol;
      const float bv = bias[n];
#pragma unroll
      for (int p = 0; p < 4; ++p)
        Out[(size_t)(m + p) * En + n] = acc[i][j][p] + bv;
    }
  }
}

// ---------------- Differential flash attention: pipelined, R20 ----------
// grid (512), block 256 (4 waves: stream st=w>>1, row-half wh=w&1).
// Carry s4 = QK[t] in regs across the barrier. Per iter t:
//   stage K[t+2] (3-buf rot) + V[t+1] (2-buf) -> QK[t+1] (indep MFMAs)
//   -> softmax[t] (+mask) -> PV[t] -> vmcnt(0)+barrier.
// LDS shorts: K 3x4096 [0,12288) | V 2x4096 [12288,20480) | P [20480+w*576).
__global__ __launch_bounds__(256, 2)
void diff_attn13(const short* __restrict__ Qg, const short* __restrict__ Kg,
                 const short* __restrict__ Vtg,
                 const float* __restrict__ lq1, const float* __restrict__ lk1,
                 const float* __restrict__ lq2, const float* __restrict__ lk2,
                 short* __restrict__ ctxb) {
  __shared__ __align__(16) short pool[22784];

  const int lin = blockIdx.x;
  const int h = lin & 7;            // XCD-resident head
  const int idx = lin >> 3;
  const int b = idx >> 5;
  const int x = idx & 31;
  const int tid = threadIdx.x;
  const int lane = tid & 63;
  const int w = tid >> 6;
  const int st = w >> 1, wh = w & 1;
  const int fr = lane & 15, hi = lane >> 4;
  const int swz = fr & 7;
  const int swv = (fr ^ (fr >> 2)) & 3;
  const size_t basebh = (size_t)(b * Hn + h) * Tn * 128;

  // lambda: wave-parallel over the 64 dims
  float lbd;
  {
    float a1 = lq1[h * 64 + lane] * lk1[h * 64 + lane];
    float a2 = lq2[h * 64 + lane] * lk2[h * 64 + lane];
#pragma unroll
    for (int off = 1; off <= 32; off <<= 1) {
      a1 += __shfl_xor(a1, off);
      a2 += __shfl_xor(a2, off);
    }
    lbd = __expf(a1) - __expf(a2) + LAMBDA_INIT;
  }

  // staging source offsets (linear LDS dest; swizzle via source permutation)
  int ksrc[2], vsrc[2], dsto[2];
#pragma unroll
  for (int j = 0; j < 2; ++j) {
    const int ob = j * 4096 + tid * 16;  // byte offset within 8KB tile
    { const int s = ob >> 8, cp = (ob >> 4) & 15, c = cp ^ (s & 7);
      ksrc[j] = s * 128 + c * 8; }
    { const int d = ob >> 6, cp = (ob >> 4) & 3,
          c = cp ^ ((d ^ (d >> 2)) & 3);
      vsrc[j] = d * Tn + c * 8; }
    dsto[j] = (j * 4096 + w * 1024) >> 1;  // shorts, wave-uniform
  }
  const short* kgb = Kg + basebh;
  const short* vgb = Vtg + basebh;

#define STAGE_K(BUF, S0)                                                 \
  {                                                                      \
    const short* kb_ = kgb + (size_t)(S0) * 128;                         \
    _Pragma("unroll") for (int j = 0; j < 2; ++j)                        \
      gload16(kb_ + ksrc[j], pool + (BUF) * 4096 + dsto[j]);             \
  }
#define STAGE_V(BUF, S0)                                                 \
  {                                                                      \
    const short* vb_ = vgb + (S0);                                       \
    _Pragma("unroll") for (int j = 0; j < 2; ++j)                        \
      gload16(vb_ + vsrc[j], pool + 12288 + (BUF) * 4096 + dsto[j]);     \
  }

  short8 ones;
#pragma unroll
  for (int e = 0; e < 8; ++e) ones[e] = (short)0x3F80;  // bf16 1.0
  short* Plw = pool + 20480 + w * 576;                  // [16][36]

  auto phase = [&](int qi) {
    const int q0 = qi * 32;
    const int NT = min(Tn / 32, qi + 2);   // NT >= 2 always
    const int tmin = q0 + wh * 16;
    const int tbase = tmin + hi * 4;

    short8 qf[2];
    {
      const short* qp = Qg + basebh + (size_t)(tmin + fr) * 128 + st * 64;
      qf[0] = *(const short8*)(qp + hi * 8);
      qf[1] = *(const short8*)(qp + 32 + hi * 8);
    }
    f32x4 o[8] = {};
    f32x4 ol = {};

    // QK for tile tt from K buffer tt%3 (resident + drained by caller)
    auto qk = [&](int tt, f32x4(&s)[2]) {
      const short* Kb = pool + (tt % 3) * 4096;
      __builtin_amdgcn_s_setprio(1);
#pragma unroll
      for (int sb = 0; sb < 2; ++sb) {
        const int rb = (sb * 16 + fr) * 128;
#pragma unroll
        for (int kp = 0; kp < 2; ++kp) {
          const short8 kb = *(const short8*)
              &Kb[rb + ((st * 8 + ((kp * 4 + hi) ^ swz)) << 3)];
          s[sb] = __builtin_amdgcn_mfma_f32_16x16x32_bf16(qf[kp], kb,
                                                          s[sb], 0, 0, 0);
        }
      }
      __builtin_amdgcn_s_setprio(0);
    };

    // prologue: tiles 0,1 (K) + tile 0 (V) staged and drained; QK[0]
    STAGE_K(0, 0);
    STAGE_V(0, 0);
    STAGE_K(1, 32);
    __builtin_amdgcn_sched_barrier(0);
    asm volatile("s_waitcnt vmcnt(0)" ::: "memory");
    __builtin_amdgcn_sched_barrier(0);
    __builtin_amdgcn_s_barrier();

    f32x4 s4[2] = {};
    qk(0, s4);

    for (int t = 0; t < NT; ++t) {
      const int s0 = t * 32;
      if (t + 2 < NT) STAGE_K((t + 2) % 3, (t + 2) * 32);
      if (t + 1 < NT) STAGE_V((t + 1) & 1, (t + 1) * 32);

      // ---- QK for NEXT tile: independent MFMAs cover softmax[t] latency
      f32x4 s4n[2] = {};
      const bool nact = (t + 1 < NT) && ((t + 1) * 32 <= tmin + 16);
      if (nact) qk(t + 1, s4n);

      if (s0 <= tmin + 16) {
        const short* Vb = pool + 12288 + (t & 1) * 4096;
        const bool interior = (tmin - s0) >= 30;
        if (!interior) {
#pragma unroll
          for (int sb = 0; sb < 2; ++sb) {
            const int sg = s0 + sb * 16 + fr;
#pragma unroll
            for (int p = 0; p < 4; ++p)
              if (sg > tbase + p + 1) s4[sb][p] = -1e30f;
          }
        }

        // ---- fixed-shift softmax: p = exp2(s - 12)
#pragma unroll
        for (int sb = 0; sb < 2; ++sb)
#pragma unroll
          for (int p = 0; p < 4; ++p)
            Plw[(hi * 4 + p) * 36 + sb * 16 + fr] =
                f2bf(exp2f(s4[sb][p] - 12.0f));

        // ---- PV: O^T += V^T * P ; l += 1^T * P
        const short8 pf = *(const short8*)&Plw[fr * 36 + hi * 8];
        __builtin_amdgcn_s_setprio(1);
        ol = __builtin_amdgcn_mfma_f32_16x16x32_bf16(ones, pf, ol, 0, 0, 0);
#pragma unroll
        for (int dblk = 0; dblk < 8; ++dblk) {
          const short8 va = *(const short8*)
              &Vb[(dblk * 16 + fr) * 32 + ((hi ^ swv) << 3)];
          o[dblk] = __builtin_amdgcn_mfma_f32_16x16x32_bf16(va, pf, o[dblk],
                                                            0, 0, 0);
        }
        __builtin_amdgcn_s_setprio(0);
      }

      s4[0] = s4n[0];
      s4[1] = s4n[1];

      // single sync point per tile: staged loads drained + reads retired.
      __builtin_amdgcn_sched_barrier(0);
      asm volatile("s_waitcnt vmcnt(0)" ::: "memory");
      __builtin_amdgcn_sched_barrier(0);
      __builtin_amdgcn_s_barrier();
    }

    // ---- epilogue: combine streams via LDS (aliases drained K/V pool)
    const float lr = ol[0];
    float* O2L = (float*)pool;  // [wh][d][t] stride 17 = 17408B
    if (st == 1) {
      const float c2 = (1.0f - LAMBDA_INIT) * lbd / lr;
#pragma unroll
      for (int dblk = 0; dblk < 8; ++dblk)
#pragma unroll
        for (int e = 0; e < 4; ++e)
          O2L[wh * 2176 + (dblk * 16 + hi * 4 + e) * 17 + fr] =
              c2 * o[dblk][e];
    }
    __syncthreads();
    if (st == 0) {
      const float c1 = (1.0f - LAMBDA_INIT) / lr;
      const int t = tmin + fr;
      short* dst = ctxb + ((size_t)b * Tn + t) * En + h * 128;
#pragma unroll
      for (int dblk = 0; dblk < 8; ++dblk) {
        s16x4 pk;
#pragma unroll
        for (int e = 0; e < 4; ++e)
          pk[e] = f2bf(c1 * o[dblk][e] -
                       O2L[wh * 2176 + (dblk * 16 + hi * 4 + e) * 17 + fr]);
        *(s16x4*)&dst[dblk * 16 + hi * 4] = pk;
      }
    }
    __syncthreads();  // O2L reads done before next phase restages
  };

  phase(63 - x);  // heavy q-tile
  phase(x);       // light q-tile
#undef STAGE_K
#undef STAGE_V
}

extern "C" void kernel_launch(void* const* d_in, const int* in_sizes, int n_in,
                              void* d_out, int out_size, void* d_ws, size_t ws_size,
                              hipStream_t stream) {
  const float* q   = (const float*)d_in[0];
  const float* k   = (const float*)d_in[1];
  const float* v   = (const float*)d_in[2];
  const float* Wq  = (const float*)d_in[3];
  const float* Wk  = (const float*)d_in[4];
  const float* Wv  = (const float*)d_in[5];
  const float* lq1 = (const float*)d_in[6];
  const float* lk1 = (const float*)d_in[7];
  const float* lq2 = (const float*)d_in[8];
  const float* lk2 = (const float*)d_in[9];
  const float* Wp  = (const float*)d_in[10];
  const float* bp  = (const float*)d_in[11];

  short* ws = (short*)d_ws;
  short* qbf = ws;                 // [2,2048,1024] bf16; later aliased by ctx
  short* kbf = ws + SZb;
  short* vbf = ws + 2 * SZb;
  short* Qb  = ws + 3 * SZb;
  short* Kb  = ws + 4 * SZb;
  short* Vtb = ws + 5 * SZb;
  short* WT  = ws + 6 * SZb;       // WqT|WkT|WvT|WpT, each WSZ
  short* ctxb = qbf;               // qbf dead after qkv_mfma2

  prep<<<dim3(7168), dim3(256), 0, stream>>>(q, k, v, Wq, Wk, Wv, Wp,
                                             ws, WT);
  qkv_mfma2<<<dim3(32, 8, 3), dim3(256), 0, stream>>>(qbf, kbf, vbf, WT,
                                                      Qb, Kb, Vtb);
  diff_attn13<<<dim3(512), dim3(256), 0, stream>>>(Qb, Kb, Vtb,
                                                   lq1, lk1, lq2, lk2, ctxb);
  proj_mfma2<<<dim3(64, 8), dim3(256), 0, stream>>>(ctxb, WT + 3 * WSZ, bp,
                                                    (float*)d_out);
}

// Round 21
// 142.469 us; speedup vs baseline: 1.0365x; 1.0365x over previous
//
#include <hip/hip_runtime.h>
#include <hip/hip_bf16.h>

// MultiDiffHeadAttention. B=2, T=2048, E=1024, H=8, HS=64, DO=128.
// mask = tril(ones, diagonal=1): (t,s) allowed iff s <= t+1.
// R21 = final: exact R19/R16 (best measured: 142.9-143.2us).
// Converged configuration after 20 rounds:
//  - prep: merged cvt(q,k,v)->bf16 + W->W^T bf16 transpose (memory-floor)
//  - qkv/proj: pure-bf16 dual-gload16 MFMA pipelines, counted vmcnt (R13)
//  - attention: single-barrier KVBLK=32 dbuf, fixed-shift exp2 softmax,
//    ones-MFMA row-sums, XCD-resident heads, balanced q-pairing (R16);
//    81us plateau confirmed across 9 structural variants.

constexpr int Tn = 2048;
constexpr int En = 1024;
constexpr int Hn = 8;
constexpr float LAMBDA_INIT = 0.8f;
// 0.125 (HS^-0.5) * log2(e), folded into Q at projection time.
constexpr float QSCALE = 0.18033688011112042f;
constexpr size_t SZb = (size_t)2 * Tn * En;      // 4,194,304 elems
constexpr size_t WSZ = (size_t)En * En;          // 1,048,576 elems

typedef __attribute__((ext_vector_type(8))) short short8;
typedef __attribute__((ext_vector_type(4))) short s16x4;
typedef __attribute__((ext_vector_type(4))) float f32x4;

__device__ __forceinline__ short f2bf(float x) {
  union { __hip_bfloat16 h; short s; } u;
  u.h = __float2bfloat16(x);
  return u.s;
}
__device__ __forceinline__ void gload16(const short* g, short* l) {
  __builtin_amdgcn_global_load_lds(
      (const __attribute__((address_space(1))) void*)g,
      (__attribute__((address_space(3))) void*)l, 16, 0, 0);
}

// ---------------- prepass (merged): cvt q/k/v + transpose weights -------
// grid 7168: ids [0,6144) = cvt (by=id/2048, bx=id%2048); [6144,7168) = twt.
__global__ __launch_bounds__(256)
void prep(const float* __restrict__ q, const float* __restrict__ k,
          const float* __restrict__ v,
          const float* __restrict__ Wq, const float* __restrict__ Wk,
          const float* __restrict__ Wv, const float* __restrict__ Wp,
          short* __restrict__ ws, short* __restrict__ WT) {
  __shared__ float tl[64][65];
  const int id = blockIdx.x;
  const int tid = threadIdx.x;
  if (id < 6144) {
    const int by = id >> 11;          // 0..2 (q/k/v)
    const int bx = id & 2047;
    const float* src = (by == 0) ? q : (by == 1) ? k : v;
    short* dst = ws + (size_t)by * SZb;
    const size_t i = ((size_t)bx * 256 + tid) * 8;
    float4 a = *(const float4*)&src[i];
    float4 b = *(const float4*)&src[i + 4];
    short8 o;
    o[0] = f2bf(a.x); o[1] = f2bf(a.y); o[2] = f2bf(a.z); o[3] = f2bf(a.w);
    o[4] = f2bf(b.x); o[5] = f2bf(b.y); o[6] = f2bf(b.z); o[7] = f2bf(b.w);
    *(short8*)&dst[i] = o;
    return;
  }
  const int wid = id - 6144;          // 0..1023
  const float* src;
  short* dst;
  int r0, c0, C;
  if (wid < 768) {
    const int wi = wid >> 8;
    const float* W = (wi == 0) ? Wq : (wi == 1) ? Wk : Wv;
    const int rem = wid & 255;
    const int h = rem >> 5;
    const int tile = rem & 31;        // 16 k-tiles x 2 n-tiles
    r0 = (tile >> 1) * 64;
    c0 = (tile & 1) * 64;
    C = 128;
    src = W + (size_t)h * En * 128;
    dst = WT + (size_t)wi * WSZ + (size_t)h * 128 * En;
  } else {
    const int idx = wid - 768;        // 16x16 tiles
    r0 = (idx >> 4) * 64;
    c0 = (idx & 15) * 64;
    C = En;
    src = Wp;
    dst = WT + 3 * WSZ;
  }
  const int r = tid >> 2, cc = (tid & 3) * 16;
#pragma unroll
  for (int j = 0; j < 4; ++j) {
    const float4 x = *(const float4*)&src[(size_t)(r0 + r) * C + c0 + cc + j * 4];
    tl[r][cc + j * 4 + 0] = x.x;
    tl[r][cc + j * 4 + 1] = x.y;
    tl[r][cc + j * 4 + 2] = x.z;
    tl[r][cc + j * 4 + 3] = x.w;
  }
  __syncthreads();
  const int c = tid >> 2, rc = (tid & 3) * 16;
  short8 o0, o1;
#pragma unroll
  for (int e = 0; e < 8; ++e) {
    o0[e] = f2bf(tl[rc + e][c]);
    o1[e] = f2bf(tl[rc + 8 + e][c]);
  }
  *(short8*)&dst[(size_t)(c0 + c) * En + r0 + rc] = o0;
  *(short8*)&dst[(size_t)(c0 + c) * En + r0 + rc + 8] = o1;
}

// ---------------- QKV projection: pure-bf16 gload_lds MFMA (R13) --------
__global__ __launch_bounds__(256)
void qkv_mfma2(const short* __restrict__ Xq, const short* __restrict__ Xk,
               const short* __restrict__ Xv, const short* __restrict__ WT,
               short* __restrict__ Qo, short* __restrict__ Ko,
               short* __restrict__ Vto) {
  __shared__ __align__(16) short As[2][4096];   // [row][32]
  __shared__ __align__(16) short Bs2[2][4096];  // [n][32]
  const int which = blockIdx.z;
  const short* X = (which == 0) ? Xq : (which == 1) ? Xk : Xv;
  const int head = blockIdx.y;
  const int m0 = blockIdx.x * 128;
  const short* Bt = WT + (size_t)which * WSZ + (size_t)head * 128 * En;
  const float oscale = (which == 0) ? QSCALE : 1.0f;

  const int tid = threadIdx.x;
  const int lane = tid & 63;
  const int w = tid >> 6, wr = w >> 1, wc = w & 1;
  const int fr = lane & 15, fk = (lane >> 4) * 8;
  const int srow = tid >> 2, sch = (tid & 3) * 8;  // staging row/chunk
  const int wdst = w * 512;                        // wave-uniform LDS base

#define QSTAGE(BUF, K0)                                                  \
  {                                                                      \
    _Pragma("unroll") for (int j = 0; j < 2; ++j) {                      \
      gload16(&X[(size_t)(m0 + j * 64 + srow) * En + (K0) + sch],        \
              &As[BUF][j * 2048 + wdst]);                                \
      gload16(&Bt[(size_t)(j * 64 + srow) * En + (K0) + sch],            \
              &Bs2[BUF][j * 2048 + wdst]);                               \
    }                                                                    \
  }

  f32x4 acc[4][4] = {};
  QSTAGE(0, 0);
  for (int k0 = 0; k0 < En; k0 += 32) {
    const int cur = (k0 >> 5) & 1;
    if (k0 + 32 < En) {
      QSTAGE(cur ^ 1, k0 + 32);
      __builtin_amdgcn_sched_barrier(0);
      asm volatile("s_waitcnt vmcnt(4)" ::: "memory");
      __builtin_amdgcn_sched_barrier(0);
    } else {
      __builtin_amdgcn_sched_barrier(0);
      asm volatile("s_waitcnt vmcnt(0)" ::: "memory");
      __builtin_amdgcn_sched_barrier(0);
    }
    __builtin_amdgcn_s_barrier();  // tile cur in LDS for all waves

    short8 a[4], b[4];
#pragma unroll
    for (int i = 0; i < 4; ++i)
      a[i] = *(const short8*)&As[cur][(wr * 64 + i * 16 + fr) * 32 + fk];
#pragma unroll
    for (int j = 0; j < 4; ++j)
      b[j] = *(const short8*)&Bs2[cur][(wc * 64 + j * 16 + fr) * 32 + fk];
#pragma unroll
    for (int i = 0; i < 4; ++i)
#pragma unroll
      for (int j = 0; j < 4; ++j)
        acc[i][j] = __builtin_amdgcn_mfma_f32_16x16x32_bf16(a[i], b[j],
                                                            acc[i][j], 0, 0, 0);
    __builtin_amdgcn_s_barrier();  // reads of cur retired before restage
  }
#undef QSTAGE

  const int crow = (lane >> 4) * 4, ccol = lane & 15;
  if (which == 2) {
#pragma unroll
    for (int i = 0; i < 4; ++i) {
      const int m = m0 + wr * 64 + i * 16 + crow;
      const int bb = m >> 11, t = m & (Tn - 1);
#pragma unroll
      for (int j = 0; j < 4; ++j) {
        const int d = wc * 64 + j * 16 + ccol;
        s16x4 pk;
#pragma unroll
        for (int p = 0; p < 4; ++p) pk[p] = f2bf(acc[i][j][p]);
        *(s16x4*)&Vto[((size_t)(bb * Hn + head) * 128 + d) * Tn + t] = pk;
      }
    }
  } else {
    short* Out = (which == 0) ? Qo : Ko;
#pragma unroll
    for (int i = 0; i < 4; ++i) {
      const int m = m0 + wr * 64 + i * 16 + crow;
      const int bb = m >> 11, t = m & (Tn - 1);
      short* dst = Out + ((size_t)(bb * Hn + head) * Tn + t) * 128;
#pragma unroll
      for (int j = 0; j < 4; ++j) {
        const int d = wc * 64 + j * 16 + ccol;
#pragma unroll
        for (int p = 0; p < 4; ++p)
          dst[(size_t)p * 128 + d] = f2bf(acc[i][j][p] * oscale);
      }
    }
  }
}

// ---------------- Output projection: pure-bf16 gload_lds MFMA (R13) -----
__global__ __launch_bounds__(256)
void proj_mfma2(const short* __restrict__ Xb, const short* __restrict__ WpT,
                const float* __restrict__ bias, float* __restrict__ Out) {
  __shared__ __align__(16) short As[2][2048];   // [64][32]
  __shared__ __align__(16) short Bs2[2][4096];  // [128][32]
  const int m0 = blockIdx.x * 64;
  const int n0 = blockIdx.y * 128;

  const int tid = threadIdx.x;
  const int lane = tid & 63;
  const int w = tid >> 6, wr = w >> 1, wc = w & 1;
  const int fr = lane & 15, fk = (lane >> 4) * 8;
  const int srow = tid >> 2, sch = (tid & 3) * 8;
  const int wdst = w * 512;

#define PSTAGE(BUF, K0)                                                  \
  {                                                                      \
    gload16(&Xb[(size_t)(m0 + srow) * En + (K0) + sch],                  \
            &As[BUF][wdst]);                                             \
    _Pragma("unroll") for (int j = 0; j < 2; ++j)                        \
      gload16(&WpT[(size_t)(n0 + j * 64 + srow) * En + (K0) + sch],      \
              &Bs2[BUF][j * 2048 + wdst]);                               \
  }

  f32x4 acc[2][4] = {};
  PSTAGE(0, 0);
  for (int k0 = 0; k0 < En; k0 += 32) {
    const int cur = (k0 >> 5) & 1;
    if (k0 + 32 < En) {
      PSTAGE(cur ^ 1, k0 + 32);
      __builtin_amdgcn_sched_barrier(0);
      asm volatile("s_waitcnt vmcnt(3)" ::: "memory");
      __builtin_amdgcn_sched_barrier(0);
    } else {
      __builtin_amdgcn_sched_barrier(0);
      asm volatile("s_waitcnt vmcnt(0)" ::: "memory");
      __builtin_amdgcn_sched_barrier(0);
    }
    __builtin_amdgcn_s_barrier();

    short8 a[2], b[4];
#pragma unroll
    for (int i = 0; i < 2; ++i)
      a[i] = *(const short8*)&As[cur][(wr * 32 + i * 16 + fr) * 32 + fk];
#pragma unroll
    for (int j = 0; j < 4; ++j)
      b[j] = *(const short8*)&Bs2[cur][(wc * 64 + j * 16 + fr) * 32 + fk];
#pragma unroll
    for (int i = 0; i < 2; ++i)
#pragma unroll
      for (int j = 0; j < 4; ++j)
        acc[i][j] = __builtin_amdgcn_mfma_f32_16x16x32_bf16(a[i], b[j],
                                                            acc[i][j], 0, 0, 0);
    __builtin_amdgcn_s_barrier();
  }
#undef PSTAGE

  const int crow = (lane >> 4) * 4, ccol = lane & 15;
#pragma unroll
  for (int i = 0; i < 2; ++i) {
    const int m = m0 + wr * 32 + i * 16 + crow;
#pragma unroll
    for (int j = 0; j < 4; ++j) {
      const int n = n0 + wc * 64 + j * 16 + ccol;
      const float bv = bias[n];
#pragma unroll
      for (int p = 0; p < 4; ++p)
        Out[(size_t)(m + p) * En + n] = acc[i][j][p] + bv;
    }
  }
}

// ---------------- Differential flash attention: single-barrier (R16) ----
// grid (512), block 256 (4 waves: stream st=w>>1, row-half wh=w&1).
// lin->(xcd=h, b, x); q-tiles {63-x, x} sequential (equal work). KVBLK=32
// dbuf. STAGE(next) -> compute(cur) -> vmcnt(0)+ONE barrier per tile.
__global__ __launch_bounds__(256, 4)
void diff_attn11(const short* __restrict__ Qg, const short* __restrict__ Kg,
                 const short* __restrict__ Vtg,
                 const float* __restrict__ lq1, const float* __restrict__ lk1,
                 const float* __restrict__ lq2, const float* __restrict__ lk2,
                 short* __restrict__ ctxb) {
  __shared__ __align__(16) short pool[18688];

  const int lin = blockIdx.x;
  const int h = lin & 7;            // XCD-resident head
  const int idx = lin >> 3;
  const int b = idx >> 5;
  const int x = idx & 31;
  const int tid = threadIdx.x;
  const int lane = tid & 63;
  const int w = tid >> 6;
  const int st = w >> 1, wh = w & 1;
  const int fr = lane & 15, hi = lane >> 4;
  const int swz = fr & 7;
  const int swv = (fr ^ (fr >> 2)) & 3;
  const size_t basebh = (size_t)(b * Hn + h) * Tn * 128;

  // lambda: wave-parallel over the 64 dims
  float lbd;
  {
    float a1 = lq1[h * 64 + lane] * lk1[h * 64 + lane];
    float a2 = lq2[h * 64 + lane] * lk2[h * 64 + lane];
#pragma unroll
    for (int off = 1; off <= 32; off <<= 1) {
      a1 += __shfl_xor(a1, off);
      a2 += __shfl_xor(a2, off);
    }
    lbd = __expf(a1) - __expf(a2) + LAMBDA_INIT;
  }

  // staging source offsets (linear LDS dest; swizzle via source permutation)
  int ksrc[2], vsrc[2], dsto[2];
#pragma unroll
  for (int j = 0; j < 2; ++j) {
    const int ob = j * 4096 + tid * 16;  // byte offset within 8KB tile
    { const int s = ob >> 8, cp = (ob >> 4) & 15, c = cp ^ (s & 7);
      ksrc[j] = s * 128 + c * 8; }
    { const int d = ob >> 6, cp = (ob >> 4) & 3,
          c = cp ^ ((d ^ (d >> 2)) & 3);
      vsrc[j] = d * Tn + c * 8; }
    dsto[j] = (j * 4096 + w * 1024) >> 1;  // shorts, wave-uniform
  }
  const short* kgb = Kg + basebh;
  const short* vgb = Vtg + basebh;

#define STAGE(BUF, S0)                                                   \
  {                                                                      \
    const short* kb_ = kgb + (size_t)(S0) * 128;                         \
    const short* vb_ = vgb + (S0);                                       \
    _Pragma("unroll") for (int j = 0; j < 2; ++j) {                      \
      gload16(kb_ + ksrc[j], pool + (BUF) * 4096 + dsto[j]);             \
      gload16(vb_ + vsrc[j], pool + 8192 + (BUF) * 4096 + dsto[j]);      \
    }                                                                    \
  }

  short8 ones;
#pragma unroll
  for (int e = 0; e < 8; ++e) ones[e] = (short)0x3F80;  // bf16 1.0
  short* Plw = pool + 16384 + w * 576;                  // [16][36]

  auto phase = [&](int qi) {
    const int q0 = qi * 32;
    const int NT = min(Tn / 32, qi + 2);
    const int tmin = q0 + wh * 16;
    const int tbase = tmin + hi * 4;

    short8 qf[2];
    {
      const short* qp = Qg + basebh + (size_t)(tmin + fr) * 128 + st * 64;
      qf[0] = *(const short8*)(qp + hi * 8);
      qf[1] = *(const short8*)(qp + 32 + hi * 8);
    }
    f32x4 o[8] = {};
    f32x4 ol = {};

    // prologue: tile 0 staged and drained
    STAGE(0, 0);
    __builtin_amdgcn_sched_barrier(0);
    asm volatile("s_waitcnt vmcnt(0)" ::: "memory");
    __builtin_amdgcn_sched_barrier(0);
    __builtin_amdgcn_s_barrier();

    int cur = 0;
    for (int t = 0; t < NT; ++t) {
      const int s0 = t * 32;
      if (t + 1 < NT) STAGE(cur ^ 1, s0 + 32);  // loads land during compute

      if (s0 <= tmin + 16) {
        const short* Kb = pool + cur * 4096;
        const short* Vb = pool + 8192 + cur * 4096;
        const bool interior = (tmin - s0) >= 30;

        // ---- QK^T: S[t=hi*4+p][s=sb*16+fr]
        f32x4 s4[2] = {};
        __builtin_amdgcn_s_setprio(1);
#pragma unroll
        for (int sb = 0; sb < 2; ++sb) {
          const int rb = (sb * 16 + fr) * 128;
#pragma unroll
          for (int kp = 0; kp < 2; ++kp) {
            const short8 kb = *(const short8*)
                &Kb[rb + ((st * 8 + ((kp * 4 + hi) ^ swz)) << 3)];
            s4[sb] = __builtin_amdgcn_mfma_f32_16x16x32_bf16(qf[kp], kb,
                                                             s4[sb], 0, 0, 0);
          }
        }
        __builtin_amdgcn_s_setprio(0);
        if (!interior) {
#pragma unroll
          for (int sb = 0; sb < 2; ++sb) {
            const int sg = s0 + sb * 16 + fr;
#pragma unroll
            for (int p = 0; p < 4; ++p)
              if (sg > tbase + p + 1) s4[sb][p] = -1e30f;
          }
        }

        // ---- fixed-shift softmax: p = exp2(s - 12)
#pragma unroll
        for (int sb = 0; sb < 2; ++sb)
#pragma unroll
          for (int p = 0; p < 4; ++p)
            Plw[(hi * 4 + p) * 36 + sb * 16 + fr] =
                f2bf(exp2f(s4[sb][p] - 12.0f));

        // ---- PV: O^T += V^T * P ; l += 1^T * P
        const short8 pf = *(const short8*)&Plw[fr * 36 + hi * 8];
        __builtin_amdgcn_s_setprio(1);
        ol = __builtin_amdgcn_mfma_f32_16x16x32_bf16(ones, pf, ol, 0, 0, 0);
#pragma unroll
        for (int dblk = 0; dblk < 8; ++dblk) {
          const short8 va = *(const short8*)
              &Vb[(dblk * 16 + fr) * 32 + ((hi ^ swv) << 3)];
          o[dblk] = __builtin_amdgcn_mfma_f32_16x16x32_bf16(va, pf, o[dblk],
                                                            0, 0, 0);
        }
        __builtin_amdgcn_s_setprio(0);
      }

      // single sync point per tile: next tile's loads drained (they had the
      // whole compute phase to land) + this tile's reads retired.
      __builtin_amdgcn_sched_barrier(0);
      asm volatile("s_waitcnt vmcnt(0)" ::: "memory");
      __builtin_amdgcn_sched_barrier(0);
      __builtin_amdgcn_s_barrier();
      cur ^= 1;
    }

    // ---- epilogue: combine streams via LDS (aliases drained K/V pool)
    const float lr = ol[0];
    float* O2L = (float*)pool;  // [wh][d][t] stride 17 = 17408B
    if (st == 1) {
      const float c2 = (1.0f - LAMBDA_INIT) * lbd / lr;
#pragma unroll
      for (int dblk = 0; dblk < 8; ++dblk)
#pragma unroll
        for (int e = 0; e < 4; ++e)
          O2L[wh * 2176 + (dblk * 16 + hi * 4 + e) * 17 + fr] =
              c2 * o[dblk][e];
    }
    __syncthreads();
    if (st == 0) {
      const float c1 = (1.0f - LAMBDA_INIT) / lr;
      const int t = tmin + fr;
      short* dst = ctxb + ((size_t)b * Tn + t) * En + h * 128;
#pragma unroll
      for (int dblk = 0; dblk < 8; ++dblk) {
        s16x4 pk;
#pragma unroll
        for (int e = 0; e < 4; ++e)
          pk[e] = f2bf(c1 * o[dblk][e] -
                       O2L[wh * 2176 + (dblk * 16 + hi * 4 + e) * 17 + fr]);
        *(s16x4*)&dst[dblk * 16 + hi * 4] = pk;
      }
    }
    __syncthreads();  // O2L reads done before next phase restages
  };

  phase(63 - x);  // heavy q-tile
  phase(x);       // light q-tile
#undef STAGE
}

extern "C" void kernel_launch(void* const* d_in, const int* in_sizes, int n_in,
                              void* d_out, int out_size, void* d_ws, size_t ws_size,
                              hipStream_t stream) {
  const float* q   = (const float*)d_in[0];
  const float* k   = (const float*)d_in[1];
  const float* v   = (const float*)d_in[2];
  const float* Wq  = (const float*)d_in[3];
  const float* Wk  = (const float*)d_in[4];
  const float* Wv  = (const float*)d_in[5];
  const float* lq1 = (const float*)d_in[6];
  const float* lk1 = (const float*)d_in[7];
  const float* lq2 = (const float*)d_in[8];
  const float* lk2 = (const float*)d_in[9];
  const float* Wp  = (const float*)d_in[10];
  const float* bp  = (const float*)d_in[11];

  short* ws = (short*)d_ws;
  short* qbf = ws;                 // [2,2048,1024] bf16; later aliased by ctx
  short* kbf = ws + SZb;
  short* vbf = ws + 2 * SZb;
  short* Qb  = ws + 3 * SZb;
  short* Kb  = ws + 4 * SZb;
  short* Vtb = ws + 5 * SZb;
  short* WT  = ws + 6 * SZb;       // WqT|WkT|WvT|WpT, each WSZ
  short* ctxb = qbf;               // qbf dead after qkv_mfma2

  prep<<<dim3(7168), dim3(256), 0, stream>>>(q, k, v, Wq, Wk, Wv, Wp,
                                             ws, WT);
  qkv_mfma2<<<dim3(32, 8, 3), dim3(256), 0, stream>>>(qbf, kbf, vbf, WT,
                                                      Qb, Kb, Vtb);
  diff_attn11<<<dim3(512), dim3(256), 0, stream>>>(Qb, Kb, Vtb,
                                                   lq1, lk1, lq2, lk2, ctxb);
  proj_mfma2<<<dim3(64, 8), dim3(256), 0, stream>>>(ctxb, WT + 3 * WSZ, bp,
                                                    (float*)d_out);
}